// Round 2
// baseline (432.738 us; speedup 1.0000x reference)
//
#include <hip/hip_runtime.h>

#define DIM 1024
#define NHEADS 16
#define HDIM 64
#define BATCH 4
#define SEQ 2048
#define MTOT (BATCH*SEQ)      // 8192 rows
#define ATTN_SCALE 0.125f     // HEAD_DIM^-0.5

typedef __bf16 bf16;
typedef __bf16 bf16x8 __attribute__((ext_vector_type(8)));
typedef __bf16 bf16x4 __attribute__((ext_vector_type(4)));
typedef float  f32x4  __attribute__((ext_vector_type(4)));

static __device__ __forceinline__ bf16 f2bf(float f) {
  unsigned u = __builtin_bit_cast(unsigned, f);
  u = (u + 0x7FFFu + ((u >> 16) & 1u)) >> 16;   // RNE
  unsigned short s = (unsigned short)u;
  return __builtin_bit_cast(bf16, s);
}

// async global->LDS, 16B per lane, linear dest (wave base + lane*16)
#define GLD16(gp, lp) __builtin_amdgcn_global_load_lds( \
    (const __attribute__((address_space(1))) void*)(gp), \
    (__attribute__((address_space(3))) void*)(lp), 16, 0, 0)

// ---------------------------------------------------------------- fp32 -> bf16
__global__ __launch_bounds__(256) void k_cvt_x(const float* __restrict__ x,
                                               bf16* __restrict__ xb) {
  size_t i = ((size_t)blockIdx.x * 256 + threadIdx.x) * 4;
  const float4 v = *(const float4*)(x + i);
  bf16x4 o;
  o[0] = f2bf(v.x); o[1] = f2bf(v.y); o[2] = f2bf(v.z); o[3] = f2bf(v.w);
  *(bf16x4*)(xb + i) = o;
}

// ------------------------------------------- W [K=1024][C] -> Wt[C][1024] bf16
// folds per-column scale; qscale!=0 additionally folds ATTN_SCALE into cols<1024
__global__ __launch_bounds__(256) void k_prep_w(const float* __restrict__ W,
                                                const float* __restrict__ sc,
                                                bf16* __restrict__ Wt,
                                                int C, int qscale) {
  __shared__ float tile[32][33];
  const int tx = threadIdx.x, ty = threadIdx.y;      // 32 x 8
  const int c0 = blockIdx.x * 32, k0 = blockIdx.y * 32;
#pragma unroll
  for (int j = 0; j < 4; ++j)
    tile[ty + 8*j][tx] = W[(size_t)(k0 + ty + 8*j) * C + (c0 + tx)];
  __syncthreads();
#pragma unroll
  for (int j = 0; j < 4; ++j) {
    int cc = c0 + ty + 8*j;
    float s = sc[cc];
    if (qscale && cc < DIM) s *= ATTN_SCALE;
    Wt[(size_t)cc * DIM + (k0 + tx)] = f2bf(tile[tx][ty + 8*j] * s);
  }
}

// ---------------------------------------------------------------- bf16 GEMM
// C[M x Nc] = A[M x 1024] * Bt[Nc x 1024]^T ; 128x128 tile, BK=32, 4 waves.
// MODE 0: scatter qkv -> Q/K/V [B][H][N][D] bf16 (scales already folded in Bt)
// MODE 1: out fp32 = acc + g2*bp  (g2 folded in Bt)
template<int MODE>
__global__ __launch_bounds__(256) void k_gemm(const bf16* __restrict__ A,
                                              const bf16* __restrict__ Bt,
                                              int nblk,
                                              float* __restrict__ outp,
                                              const float* __restrict__ g2,
                                              const float* __restrict__ bp,
                                              bf16* __restrict__ Qb,
                                              bf16* __restrict__ Kb,
                                              bf16* __restrict__ Vb) {
  __shared__ bf16 Als[128*32];
  __shared__ bf16 Bls[128*32];
  const int bm = blockIdx.x / nblk, bn = blockIdx.x % nblk;
  const int t = threadIdx.x;
  const int lane = t & 63, wave = t >> 6;
  const int c = lane & 15, g = lane >> 4;
  const int wm = (wave >> 1) * 64, wn = (wave & 1) * 64;
  const int srow = t >> 2, schunk = t & 3;           // staging map: 64B rows
  const bf16* Ab = A  + (size_t)(bm*128) * DIM;
  const bf16* Bb = Bt + (size_t)(bn*128) * DIM;
  f32x4 acc[4][4] = {};
  for (int k0 = 0; k0 < DIM; k0 += 32) {
    __syncthreads();                                  // prior reads done
#pragma unroll
    for (int i = 0; i < 2; ++i) {
      GLD16(Ab + (size_t)(i*64 + srow)*DIM + k0 + schunk*8,
            (char*)Als + i*4096 + t*16);
      GLD16(Bb + (size_t)(i*64 + srow)*DIM + k0 + schunk*8,
            (char*)Bls + i*4096 + t*16);
    }
    __syncthreads();                                  // drains vmcnt
    bf16x8 a[4], b[4];
#pragma unroll
    for (int m = 0; m < 4; ++m)
      a[m] = *(const bf16x8*)&Als[(wm + m*16 + c)*32 + g*8];
#pragma unroll
    for (int n = 0; n < 4; ++n)
      b[n] = *(const bf16x8*)&Bls[(wn + n*16 + c)*32 + g*8];
#pragma unroll
    for (int m = 0; m < 4; ++m)
#pragma unroll
      for (int n = 0; n < 4; ++n)
        acc[m][n] = __builtin_amdgcn_mfma_f32_16x16x32_bf16(a[m], b[n], acc[m][n], 0, 0, 0);
  }
  const int cb = bn*128 + wn, rb = bm*128 + wm;
  if (MODE == 0) {
    const int which = (bn*128) >> 10;                 // block fully inside one of q/k/v
    bf16* dst = which == 0 ? Qb : (which == 1 ? Kb : Vb);
#pragma unroll
    for (int n = 0; n < 4; ++n) {
      const int colg = cb + n*16 + c;
      const int h = (colg >> 6) & 15, d = colg & 63;
      const size_t hd = (size_t)h * (SEQ*HDIM) + d;
#pragma unroll
      for (int m = 0; m < 4; ++m)
#pragma unroll
        for (int r = 0; r < 4; ++r) {
          const int row = rb + m*16 + 4*g + r;        // C/D: col=lane&15, row=4*(lane>>4)+r
          const int bb = row >> 11, nt = row & 2047;
          dst[(size_t)bb * (NHEADS*SEQ*HDIM) + hd + (size_t)nt * HDIM] = f2bf(acc[m][n][r]);
        }
    }
  } else {
#pragma unroll
    for (int n = 0; n < 4; ++n) {
      const int col = cb + n*16 + c;
      const float bias = g2[col] * bp[col];
#pragma unroll
      for (int m = 0; m < 4; ++m)
#pragma unroll
        for (int r = 0; r < 4; ++r) {
          const int row = rb + m*16 + 4*g + r;
          outp[(size_t)row * DIM + col] = acc[m][n][r] + bias;
        }
    }
  }
}

// ---------------------------------------------------------------- attention
// grid: (B*H) * (N/128). 4 waves x 32 q-rows. KV tile = 128.
// K_lds padded [128][72] (row stride 144B == 16 mod 128 -> spread banks)
// V staged transposed: Vt[64][136] so PV B-frag is contiguous ds_read_b128.
__global__ __launch_bounds__(256) void k_attn(const bf16* __restrict__ Q,
                                              const bf16* __restrict__ K,
                                              const bf16* __restrict__ V,
                                              bf16* __restrict__ O) {
  __shared__ bf16 Kls[128*72];
  __shared__ bf16 Vls[64*136];
  __shared__ bf16 Pls[4][32*136];
  const int bid = blockIdx.x;
  const int qt = bid & 15, bh = bid >> 4;
  const int t = threadIdx.x, wave = t >> 6, lane = t & 63;
  const int c = lane & 15, g = lane >> 4;
  const int wrow = wave * 32;
  const bf16* Qp = Q + ((size_t)bh * SEQ + qt*128) * HDIM;
  const bf16* Kp = K + (size_t)bh * SEQ * HDIM;
  const bf16* Vp = V + (size_t)bh * SEQ * HDIM;
  // Q fragments in registers (A-operand: row=lane&15, k=8*(lane>>4)+j)
  bf16x8 qf[2][2];
#pragma unroll
  for (int m = 0; m < 2; ++m)
#pragma unroll
    for (int kk = 0; kk < 2; ++kk)
      qf[m][kk] = *(const bf16x8*)(Qp + (size_t)(wrow + m*16 + c)*HDIM + kk*32 + g*8);
  f32x4 oacc[2][4] = {};
  float rm[2][4], rl[2][4];
#pragma unroll
  for (int m = 0; m < 2; ++m)
#pragma unroll
    for (int r = 0; r < 4; ++r) { rm[m][r] = -1e30f; rl[m][r] = 0.f; }
  const int srow = t >> 3, schunk = t & 7;            // staging: 128B rows
  for (int kv0 = 0; kv0 < SEQ; kv0 += 128) {
    __syncthreads();                                  // prior tile's reads done
#pragma unroll
    for (int i = 0; i < 4; ++i) {                     // K tile, padded rows
      const int rr = i*32 + srow;
      bf16x8 kvv = *(const bf16x8*)(Kp + (size_t)(kv0 + rr)*HDIM + schunk*8);
      *(bf16x8*)&Kls[rr*72 + schunk*8] = kvv;
    }
#pragma unroll
    for (int i = 0; i < 4; ++i) {                     // V tile, transposed
      const int mm = i*32 + srow;
      bf16x8 vv = *(const bf16x8*)(Vp + (size_t)(kv0 + mm)*HDIM + schunk*8);
#pragma unroll
      for (int jj = 0; jj < 8; ++jj)
        Vls[(schunk*8 + jj)*136 + mm] = vv[jj];
    }
    __syncthreads();
    // S = Q K^T  (B-frag: 8 contiguous d from K row (n*16+c))
    f32x4 s[2][8] = {};
#pragma unroll
    for (int kk = 0; kk < 2; ++kk)
#pragma unroll
      for (int n = 0; n < 8; ++n) {
        const bf16x8 kb = *(const bf16x8*)&Kls[(n*16 + c)*72 + kk*32 + g*8];
#pragma unroll
        for (int m = 0; m < 2; ++m)
          s[m][n] = __builtin_amdgcn_mfma_f32_16x16x32_bf16(qf[m][kk], kb, s[m][n], 0, 0, 0);
      }
    // online softmax (rows = 4g+r, reduce across the 16 lanes c)
#pragma unroll
    for (int m = 0; m < 2; ++m) {
      float mnew[4], alpha[4];
#pragma unroll
      for (int r = 0; r < 4; ++r) {
        float pm = s[m][0][r];
#pragma unroll
        for (int n = 1; n < 8; ++n) pm = fmaxf(pm, s[m][n][r]);
#pragma unroll
        for (int off = 1; off < 16; off <<= 1) pm = fmaxf(pm, __shfl_xor(pm, off, 16));
        mnew[r] = fmaxf(rm[m][r], pm);
        alpha[r] = __expf(rm[m][r] - mnew[r]);
        rm[m][r] = mnew[r];
      }
      float psum[4] = {0.f, 0.f, 0.f, 0.f};
#pragma unroll
      for (int n = 0; n < 8; ++n)
#pragma unroll
        for (int r = 0; r < 4; ++r) {
          const float p = __expf(s[m][n][r] - mnew[r]);
          psum[r] += p;
          Pls[wave][(m*16 + 4*g + r)*136 + n*16 + c] = f2bf(p);
        }
#pragma unroll
      for (int r = 0; r < 4; ++r) {
#pragma unroll
        for (int off = 1; off < 16; off <<= 1) psum[r] += __shfl_xor(psum[r], off, 16);
        rl[m][r] = rl[m][r]*alpha[r] + psum[r];
#pragma unroll
        for (int df = 0; df < 4; ++df) oacc[m][df][r] *= alpha[r];
      }
    }
    // O += P V   (A-frag from Pls rows, B-frag contiguous from Vt rows)
#pragma unroll
    for (int kf = 0; kf < 4; ++kf) {
      bf16x8 pa[2];
#pragma unroll
      for (int m = 0; m < 2; ++m)
        pa[m] = *(const bf16x8*)&Pls[wave][(m*16 + c)*136 + kf*32 + g*8];
#pragma unroll
      for (int df = 0; df < 4; ++df) {
        const bf16x8 vb = *(const bf16x8*)&Vls[(df*16 + c)*136 + kf*32 + g*8];
#pragma unroll
        for (int m = 0; m < 2; ++m)
          oacc[m][df] = __builtin_amdgcn_mfma_f32_16x16x32_bf16(pa[m], vb, oacc[m][df], 0, 0, 0);
      }
    }
  }
  // write O as [B][N][C] bf16 (token-major, ready for proj GEMM A-operand)
  const int b = bh >> 4, h = bh & 15;
#pragma unroll
  for (int m = 0; m < 2; ++m)
#pragma unroll
    for (int r = 0; r < 4; ++r) {
      const float inv = 1.0f / rl[m][r];
      const int rowg = qt*128 + wrow + m*16 + 4*g + r;
      bf16* orow = O + ((size_t)b*SEQ + rowg)*DIM + h*HDIM;
#pragma unroll
      for (int df = 0; df < 4; ++df)
        orow[df*16 + c] = f2bf(oacc[m][df][r] * inv);
    }
}

// ---------------------------------------------------------------- launch
extern "C" void kernel_launch(void* const* d_in, const int* in_sizes, int n_in,
                              void* d_out, int out_size, void* d_ws, size_t ws_size,
                              hipStream_t stream) {
  const float* x    = (const float*)d_in[0];
  const float* Wqkv = (const float*)d_in[1];
  const float* g1   = (const float*)d_in[2];
  const float* Wp   = (const float*)d_in[3];
  const float* bp   = (const float*)d_in[4];
  const float* g2   = (const float*)d_in[5];
  float* out = (float*)d_out;
  char* ws = (char*)d_ws;
  // workspace map (72 MiB): xb also reused as attention output O
  bf16* xb  = (bf16*)ws;                       // 16 MiB [8192][1024]
  bf16* Wqt = (bf16*)(ws + (16u<<20));         //  6 MiB [3072][1024]
  bf16* Wpt = (bf16*)(ws + (22u<<20));         //  2 MiB [1024][1024]
  bf16* Qb  = (bf16*)(ws + (24u<<20));         // 16 MiB [B][H][N][D]
  bf16* Kb  = (bf16*)(ws + (40u<<20));         // 16 MiB
  bf16* Vb  = (bf16*)(ws + (56u<<20));         // 16 MiB

  k_cvt_x<<<(MTOT*DIM)/1024, 256, 0, stream>>>(x, xb);
  k_prep_w<<<dim3(96, 32), dim3(32, 8), 0, stream>>>(Wqkv, g1, Wqt, 3*DIM, 1);
  k_prep_w<<<dim3(32, 32), dim3(32, 8), 0, stream>>>(Wp, g2, Wpt, DIM, 0);
  k_gemm<0><<<64*24, 256, 0, stream>>>(xb, Wqt, 24, nullptr, nullptr, nullptr, Qb, Kb, Vb);
  k_attn<<<64*16, 256, 0, stream>>>(Qb, Kb, Vb, xb);
  k_gemm<1><<<64*8, 256, 0, stream>>>(xb, Wpt, 8, out, g2, bp, nullptr, nullptr, nullptr);
}